// Round 6
// baseline (1302.465 us; speedup 1.0000x reference)
//
#include <hip/hip_runtime.h>
#include <hip/hip_bf16.h>

// Fused transformer block, one 16-wave (1024-thr) workgroup per batch element.
// Thin per-wave tiles (16 output cols/wave) -> fits 64 VGPR (proved R5, no
// spills). LDS exactly 64KB static -> 2 blocks/CU co-resident, so barrier
// drains overlap with the other block (R5 at 104KB had 1 block/CU and 47% occ
// was the ceiling). __launch_bounds__(1024,2): measured semantics arg2 =
// min-blocks/CU -> VGPR cap 512/(2*16/4) = 64.
// ws layout (bf16/ushort): [0,65536) WqT[h][d][c]; [65536,131072) WkT;
// [131072,196608) WvT; [196608,262144) WprojT[n][c]; [262144,524288) W1T[n][c];
// [524288,786432) W2T[n][k].  Requires ws_size >= 1572864 bytes.

typedef float v4f __attribute__((ext_vector_type(4)));
typedef int   v4i __attribute__((ext_vector_type(4)));
typedef float f4v __attribute__((ext_vector_type(4)));

#define DEV static __device__ __forceinline__

DEV unsigned short f2bf(float f){
  return __builtin_bit_cast(unsigned short, __float2bfloat16(f));
}

// bf16 MFMA via inline asm: layout-safe under consistent per-lane contiguous-8
// K fragments (A from [M][K] rows, B from [N][K] rows i.e. pre-transposed).
DEV v4f mfma16(v4i a, v4i b, v4f c){
  asm("v_mfma_f32_16x16x32_bf16 %0, %1, %2, %0" : "+v"(c) : "v"(a), "v"(b));
  return c;
}
// Hazard fence: asm MFMA is opaque to the hazard recognizer.
DEV v4f accfence(v4f c){
  asm("s_nop 7\n\ts_nop 3" : "+v"(c));
  return c;
}

// Swizzled LDS byte offsets (G4: XOR row bits into 16B-granule bits).
DEV int hoff(int r, int c){ return r*512 + ((c*2) ^ ((r & 7) << 4)); }  // [64][256] bf16
DEV int koff(int r, int c){ return r*128 + ((c*2) ^ ((r & 7) << 4)); }  // [*][64]  bf16

DEV unsigned long long pack4(v4f v){
  return (unsigned long long)f2bf(v[0])
       | ((unsigned long long)f2bf(v[1]) << 16)
       | ((unsigned long long)f2bf(v[2]) << 32)
       | ((unsigned long long)f2bf(v[3]) << 48);
}

DEV float rsum64(float v){
  #pragma unroll
  for (int k = 1; k < 64; k <<= 1) v += __shfl_xor(v, k);
  return v;
}
DEV float rsum16(float v){
  #pragma unroll
  for (int k = 1; k < 16; k <<= 1) v += __shfl_xor(v, k);
  return v;
}
DEV float rmax16(float v){
  #pragma unroll
  for (int k = 1; k < 16; k <<= 1) v = fmaxf(v, __shfl_xor(v, k));
  return v;
}

__global__ void prep_w(const float* __restrict__ Wq, const float* __restrict__ Wk,
                       const float* __restrict__ Wv, const float* __restrict__ Wp,
                       const float* __restrict__ W1, const float* __restrict__ W2,
                       unsigned short* __restrict__ ws){
  int t = blockIdx.x * 256 + threadIdx.x;   // grid covers exactly 786432
  float v;
  if (t < 196608){
    int seg = t >> 16, r = t & 65535;
    int c = r & 255, d = (r >> 8) & 63, h = r >> 14;
    const float* W = (seg == 0) ? Wq : ((seg == 1) ? Wk : Wv);
    v = W[h*16384 + c*64 + d];
  } else if (t < 262144){
    int r = t - 196608; int n = r >> 8, c = r & 255;
    v = Wp[c*256 + n];
  } else if (t < 524288){
    int r = t - 262144; int n = r >> 8, c = r & 255;
    v = W1[c*1024 + n];
  } else {
    int r = t - 524288; int n = r >> 10, k = r & 1023;
    v = W2[k*256 + n];
  }
  ws[t] = f2bf(v);
}

// LDS map (bytes), static 65536:
//   HLS @0      [64][256] bf16 swz : h, later h2
//   QP  @32768  [64][64]  bf16 swz : q, then P (P overwrites own q rows)
//   KT  @40960  [64][64]  bf16 swz : k
//   VT  @49152  [64][64]  bf16 swz : v^T  (rows = d, cols = s)
//   ATL @57344  [64][64]  bf16 swz : att for current head
//   Phase C: PSUM@32768(4K) PSQ@36864(4K) MU2@40960 RS2@41216 (alias QP/KT)
//   Phase D: ACT@32768 [64][256] bf16 swz (aliases QP..ATL, all dead)

__global__ __launch_bounds__(1024, 2) void blk_fwd(
    const float* __restrict__ x,
    const float* __restrict__ ln1g, const float* __restrict__ ln1b,
    const unsigned short* __restrict__ wqT,
    const unsigned short* __restrict__ wkT,
    const unsigned short* __restrict__ wvT,
    const unsigned short* __restrict__ wpT,
    const float* __restrict__ bpj,
    const float* __restrict__ ln2g, const float* __restrict__ ln2b,
    const unsigned short* __restrict__ w1T,
    const float* __restrict__ b1,
    const unsigned short* __restrict__ w2T,
    const float* __restrict__ b2,
    float* __restrict__ out)
{
  __shared__ char smb[65536] __attribute__((aligned(16)));
  char* sm = smb;
  const int HLS = 0, QP = 32768, KT = 40960, VT = 49152, ATL = 57344;
  const int PSUM = 32768, PSQ = 36864, MU2 = 40960, RS2 = 41216;
  const int ACT = 32768;

  const int b = blockIdx.x;
  const float* __restrict__ xb   = x   + (size_t)b * (64*256);
  float* __restrict__       outb = out + (size_t)b * (64*256);
  const int tid = threadIdx.x;
  const int w = tid >> 6, l = tid & 63, m = l & 15, g = l >> 4;
  const v4f zf = {0.f, 0.f, 0.f, 0.f};

  // ---------------- Phase A: LN1 -> h (bf16, LDS); 4 rows per wave ------------
  {
    f4v lg = *(const f4v*)(ln1g + 4*l);
    f4v lb = *(const f4v*)(ln1b + 4*l);
    #pragma unroll
    for (int rr = 0; rr < 4; ++rr){
      int r = w*4 + rr;
      f4v xv = *(const f4v*)(xb + r*256 + 4*l);
      float s = xv[0]+xv[1]+xv[2]+xv[3];
      float q = xv[0]*xv[0]+xv[1]*xv[1]+xv[2]*xv[2]+xv[3]*xv[3];
      s = rsum64(s); q = rsum64(q);
      float mu = s * (1.f/256.f);
      float rs = rsqrtf(q * (1.f/256.f) - mu*mu + 1e-6f);
      unsigned long long pk = 0;
      #pragma unroll
      for (int j = 0; j < 4; ++j){
        float hv = (xv[j] - mu) * rs * lg[j] + lb[j];
        pk |= (unsigned long long)f2bf(hv) << (16*j);
      }
      *(unsigned long long*)(sm + HLS + hoff(r, 4*l)) = pk;
    }
  }
  __syncthreads();

  // ---------------- Phase B: attention; sa (16 cols/wave) in regs -------------
  v4f sa[4] = {zf, zf, zf, zf};

  #pragma unroll 1
  for (int hh = 0; hh < 4; ++hh){
    // merged: proj of previous head (all 16 waves) -- reads ATL only
    if (hh > 0){
      #pragma unroll
      for (int ks = 0; ks < 2; ++ks){
        int k0 = ks*32 + 8*g;
        v4i bp = *(const v4i*)(wpT + (w*16 + m)*256 + (hh-1)*64 + k0);
        #pragma unroll
        for (int rt = 0; rt < 4; ++rt){
          v4i af = *(const v4i*)(sm + ATL + koff(rt*16 + m, k0));
          sa[rt] = mfma16(af, bp, sa[rt]);
        }
      }
    }
    // step 1: waves 0-11 compute q/k/v 16-col stripes -> QP/KT/VT
    if (w < 12){
      int tsel = w >> 2, ct = w & 3;
      const unsigned short* wsrc =
          (tsel == 0 ? wqT : (tsel == 1 ? wkT : wvT)) + hh*16384 + (ct*16 + m)*256;
      v4f acc[4] = {zf, zf, zf, zf};
      #pragma unroll
      for (int ks = 0; ks < 8; ++ks){
        int k0 = ks*32 + 8*g;
        v4i bfr = *(const v4i*)(wsrc + k0);
        #pragma unroll
        for (int rt = 0; rt < 4; ++rt){
          v4i af = *(const v4i*)(sm + HLS + hoff(rt*16 + m, k0));
          acc[rt] = mfma16(af, bfr, acc[rt]);
        }
      }
      if (tsel < 2){
        int base = (tsel == 0) ? QP : KT;
        #pragma unroll
        for (int rt = 0; rt < 4; ++rt){
          acc[rt] = accfence(acc[rt]);
          #pragma unroll
          for (int j = 0; j < 4; ++j)
            *(unsigned short*)(sm + base + koff(rt*16 + 4*g + j, ct*16 + m)) =
                f2bf(acc[rt][j]);
        }
      } else {
        #pragma unroll
        for (int rt = 0; rt < 4; ++rt){
          acc[rt] = accfence(acc[rt]);
          *(unsigned long long*)(sm + VT + koff(ct*16 + m, rt*16 + 4*g)) = pack4(acc[rt]);
        }
      }
    }
    __syncthreads();   // bar1: q,k,v^T ready; all proj(hh-1) ATL reads done

    // step 2: waves 12-15: 16-row S stripe -> softmax -> P (over own q) -> PV -> ATL
    if (w >= 12){
      int srt = w - 12;
      v4f s4[4] = {zf, zf, zf, zf};
      #pragma unroll
      for (int ks = 0; ks < 2; ++ks){
        int k0 = ks*32 + 8*g;
        v4i qf = *(const v4i*)(sm + QP + koff(srt*16 + m, k0));
        #pragma unroll
        for (int nt = 0; nt < 4; ++nt){
          v4i kf = *(const v4i*)(sm + KT + koff(nt*16 + m, k0));
          s4[nt] = mfma16(qf, kf, s4[nt]);
        }
      }
      #pragma unroll
      for (int nt = 0; nt < 4; ++nt) s4[nt] = accfence(s4[nt]);
      float mx[4] = {-3e38f, -3e38f, -3e38f, -3e38f};
      #pragma unroll
      for (int nt = 0; nt < 4; ++nt){
        #pragma unroll
        for (int j = 0; j < 4; ++j){
          int t = srt*16 + 4*g + j, ss = nt*16 + m;
          float z = s4[nt][j] * 0.125f;
          z = (ss <= t) ? z : -1e30f;
          s4[nt][j] = z;
          mx[j] = fmaxf(mx[j], z);
        }
      }
      #pragma unroll
      for (int j = 0; j < 4; ++j) mx[j] = rmax16(mx[j]);
      float sum[4] = {0.f, 0.f, 0.f, 0.f};
      #pragma unroll
      for (int nt = 0; nt < 4; ++nt){
        #pragma unroll
        for (int j = 0; j < 4; ++j){
          float p = __expf(s4[nt][j] - mx[j]);
          s4[nt][j] = p;
          sum[j] += p;
        }
      }
      #pragma unroll
      for (int j = 0; j < 4; ++j) sum[j] = 1.f / rsum16(sum[j]);
      #pragma unroll
      for (int nt = 0; nt < 4; ++nt){
        #pragma unroll
        for (int j = 0; j < 4; ++j)
          *(unsigned short*)(sm + QP + koff(srt*16 + 4*g + j, nt*16 + m)) =
              f2bf(s4[nt][j] * sum[j]);   // P overwrites own stripe's q rows
      }
      // PV (same wave reads its own fresh P; compiler orders the LDS RAW)
      v4f av[4] = {zf, zf, zf, zf};
      #pragma unroll
      for (int ks = 0; ks < 2; ++ks){
        int k0 = ks*32 + 8*g;
        v4i pf = *(const v4i*)(sm + QP + koff(srt*16 + m, k0));
        #pragma unroll
        for (int nt = 0; nt < 4; ++nt){
          v4i vf = *(const v4i*)(sm + VT + koff(nt*16 + m, k0));
          av[nt] = mfma16(pf, vf, av[nt]);
        }
      }
      #pragma unroll
      for (int nt = 0; nt < 4; ++nt) av[nt] = accfence(av[nt]);
      #pragma unroll
      for (int nt = 0; nt < 4; ++nt){
        #pragma unroll
        for (int j = 0; j < 4; ++j)
          *(unsigned short*)(sm + ATL + koff(srt*16 + 4*g + j, nt*16 + m)) =
              f2bf(av[nt][j]);
      }
    }
    __syncthreads();   // bar2: att ready; QP/KT/VT dead
  }
  // proj of last head
  {
    #pragma unroll
    for (int ks = 0; ks < 2; ++ks){
      int k0 = ks*32 + 8*g;
      v4i bp = *(const v4i*)(wpT + (w*16 + m)*256 + 3*64 + k0);
      #pragma unroll
      for (int rt = 0; rt < 4; ++rt){
        v4i af = *(const v4i*)(sm + ATL + koff(rt*16 + m, k0));
        sa[rt] = mfma16(af, bp, sa[rt]);
      }
    }
    #pragma unroll
    for (int rt = 0; rt < 4; ++rt) sa[rt] = accfence(sa[rt]);
  }

  // ---------------- Phase C: x2 = x + sa + bproj (f32 -> d_out); LN2 -> h2 ----
  {
    int c = w*16 + m;
    float bp1 = bpj[c], lg2 = ln2g[c], lb2 = ln2b[c];
    #pragma unroll
    for (int rt = 0; rt < 4; ++rt){
      #pragma unroll
      for (int j = 0; j < 4; ++j){
        int row = rt*16 + 4*g + j;
        float v = xb[row*256 + c] + sa[rt][j] + bp1;
        sa[rt][j] = v;
        outb[row*256 + c] = v;          // park x2 f32; re-read at final residual
      }
    }
    #pragma unroll
    for (int rt = 0; rt < 4; ++rt){
      #pragma unroll
      for (int j = 0; j < 4; ++j){
        float s = rsum16(sa[rt][j]);
        float q = rsum16(sa[rt][j]*sa[rt][j]);
        if (m == 0){
          int row = rt*16 + 4*g + j;
          *(float*)(sm + PSUM + row*64 + w*4) = s;   // aliases dead QP
          *(float*)(sm + PSQ  + row*64 + w*4) = q;
        }
      }
    }
    __syncthreads();
    if (tid < 64){
      float s = 0.f, q = 0.f;
      #pragma unroll
      for (int i = 0; i < 16; ++i){
        s += *(const float*)(sm + PSUM + tid*64 + i*4);
        q += *(const float*)(sm + PSQ  + tid*64 + i*4);
      }
      float mu = s * (1.f/256.f);
      float rs = rsqrtf(q * (1.f/256.f) - mu*mu + 1e-6f);
      *(float*)(sm + MU2 + tid*4) = mu;
      *(float*)(sm + RS2 + tid*4) = rs;
    }
    __syncthreads();
    #pragma unroll
    for (int rt = 0; rt < 4; ++rt){
      #pragma unroll
      for (int j = 0; j < 4; ++j){
        int row = rt*16 + 4*g + j;
        float mu = *(const float*)(sm + MU2 + row*4);
        float rs = *(const float*)(sm + RS2 + row*4);
        float h2 = (sa[rt][j] - mu) * rs * lg2 + lb2;
        *(unsigned short*)(sm + HLS + hoff(row, c)) = f2bf(h2);  // h dead
      }
    }
  }
  __syncthreads();

  // ---------------- Phase D: MLP, 4 chunks of 256; 16 cols per wave -----------
  v4f ff[4] = {zf, zf, zf, zf};
  #pragma unroll 1
  for (int ch = 0; ch < 4; ++ch){
    v4f a1[4] = {zf, zf, zf, zf};
    const unsigned short* w1p = w1T + (ch*256 + w*16 + m)*256;
    #pragma unroll
    for (int ks = 0; ks < 8; ++ks){
      int k0 = ks*32 + 8*g;
      v4i bw = *(const v4i*)(w1p + k0);
      #pragma unroll
      for (int rt = 0; rt < 4; ++rt){
        v4i af = *(const v4i*)(sm + HLS + hoff(rt*16 + m, k0));
        a1[rt] = mfma16(af, bw, a1[rt]);
      }
    }
    float b1v = b1[ch*256 + w*16 + m];
    #pragma unroll
    for (int rt = 0; rt < 4; ++rt){
      a1[rt] = accfence(a1[rt]);
      #pragma unroll
      for (int j = 0; j < 4; ++j){
        int row = rt*16 + 4*g + j;
        float v = fmaxf(a1[rt][j] + b1v, 0.f);
        *(unsigned short*)(sm + ACT + hoff(row, w*16 + m)) = f2bf(v);  // act chunk
      }
    }
    __syncthreads();
    const unsigned short* w2p = w2T + (w*16 + m)*1024 + ch*256;
    #pragma unroll
    for (int ks = 0; ks < 8; ++ks){
      int k0 = ks*32 + 8*g;
      v4i bw = *(const v4i*)(w2p + k0);
      #pragma unroll
      for (int rt = 0; rt < 4; ++rt){
        v4i af = *(const v4i*)(sm + ACT + hoff(rt*16 + m, k0));
        ff[rt] = mfma16(af, bw, ff[rt]);
      }
    }
    __syncthreads();   // protect act chunk before next GEMM1 overwrite
  }

  // ---------------- Final: out = x2 + ff + b2 (RMW of parked f32 x2) ----------
  {
    int c = w*16 + m;
    float b2v = b2[c];
    #pragma unroll
    for (int rt = 0; rt < 4; ++rt){
      ff[rt] = accfence(ff[rt]);
      #pragma unroll
      for (int j = 0; j < 4; ++j){
        int row = rt*16 + 4*g + j;
        outb[row*256 + c] += ff[rt][j] + b2v;
      }
    }
  }
}

extern "C" void kernel_launch(void* const* d_in, const int* in_sizes, int n_in,
                              void* d_out, int out_size, void* d_ws, size_t ws_size,
                              hipStream_t stream) {
  const float* x    = (const float*)d_in[0];
  const float* ln1g = (const float*)d_in[1];
  const float* ln1b = (const float*)d_in[2];
  const float* Wq   = (const float*)d_in[3];
  const float* Wk   = (const float*)d_in[4];
  const float* Wv   = (const float*)d_in[5];
  const float* Wp   = (const float*)d_in[6];
  const float* bpj  = (const float*)d_in[7];
  const float* ln2g = (const float*)d_in[8];
  const float* ln2b = (const float*)d_in[9];
  const float* W1   = (const float*)d_in[10];
  const float* b1   = (const float*)d_in[11];
  const float* W2   = (const float*)d_in[12];
  const float* b2   = (const float*)d_in[13];
  unsigned short* ws = (unsigned short*)d_ws;

  prep_w<<<3072, 256, 0, stream>>>(Wq, Wk, Wv, Wp, W1, W2, ws);
  blk_fwd<<<4096, 1024, 0, stream>>>(x, ln1g, ln1b,
                                    ws, ws + 65536, ws + 131072, ws + 196608,
                                    bpj, ln2g, ln2b,
                                    ws + 262144, b1, ws + 524288, b2,
                                    (float*)d_out);
}

// Round 8
// 965.825 us; speedup vs baseline: 1.3486x; 1.3486x over previous
//
#include <hip/hip_runtime.h>
#include <hip/hip_bf16.h>

// Fused transformer block as a 3-kernel pipeline:
//   prep_w     : f32 weights -> bf16 transposed in ws (1.5 MB only -- R7's
//                136 MB att-in-ws buffer was the correctness failure; never
//                assume ws capacity beyond what's proven).
//   attnproj_k : LN1 -> per-head (QKV -> causal softmax -> PV -> proj-accum
//                in regs) -> x2 = x + sa + bproj -> f32 in d_out. R1-proven.
//   mlp_k      : LN2(x2) -> MLP (ping-pong act, 1 barrier/chunk) -> RMW out.
// ws layout (bf16/ushort): [0,65536) WqT[h][d][c]; [65536,131072) WkT;
// [131072,196608) WvT; [196608,262144) WprojT[n][c]; [262144,524288) W1T[n][c];
// [524288,786432) W2T[n][k].  Requires ws_size >= 1572864 bytes only.

typedef float v4f __attribute__((ext_vector_type(4)));
typedef int   v4i __attribute__((ext_vector_type(4)));
typedef float f4v __attribute__((ext_vector_type(4)));
typedef unsigned long long u64;

#define DEV static __device__ __forceinline__

DEV unsigned short f2bf(float f){
  return __builtin_bit_cast(unsigned short, __float2bfloat16(f));
}

// bf16 MFMA via inline asm: layout-safe under consistent per-lane contiguous-8
// K fragments (A from [M][K] rows, B from [N][K] rows i.e. pre-transposed).
DEV v4f mfma16(v4i a, v4i b, v4f c){
  asm("v_mfma_f32_16x16x32_bf16 %0, %1, %2, %0" : "+v"(c) : "v"(a), "v"(b));
  return c;
}
// Hazard fence: asm MFMA is opaque to the hazard recognizer.
DEV v4f accfence(v4f c){
  asm("s_nop 7\n\ts_nop 3" : "+v"(c));
  return c;
}

// Swizzled LDS byte offsets (XOR row bits into 16B-granule bits).
DEV int hoff(int r, int c){ return r*512 + ((c*2) ^ ((r & 7) << 4)); }  // [64][256] bf16
DEV int koff(int r, int c){ return r*128 + ((c*2) ^ ((r & 7) << 4)); }  // [*][64]  bf16
DEV int aoff(int r, int c){ return r*256 + ((c*2) ^ ((r & 7) << 4)); }  // [64][128] bf16

DEV u64 pack4(v4f v){
  return (u64)f2bf(v[0]) | ((u64)f2bf(v[1]) << 16)
       | ((u64)f2bf(v[2]) << 32) | ((u64)f2bf(v[3]) << 48);
}

DEV float rsum64(float v){
  #pragma unroll
  for (int k = 1; k < 64; k <<= 1) v += __shfl_xor(v, k);
  return v;
}
DEV float rsum16(float v){
  #pragma unroll
  for (int k = 1; k < 16; k <<= 1) v += __shfl_xor(v, k);
  return v;
}
DEV float rmax16(float v){
  #pragma unroll
  for (int k = 1; k < 16; k <<= 1) v = fmaxf(v, __shfl_xor(v, k));
  return v;
}

__global__ void prep_w(const float* __restrict__ Wq, const float* __restrict__ Wk,
                       const float* __restrict__ Wv, const float* __restrict__ Wp,
                       const float* __restrict__ W1, const float* __restrict__ W2,
                       unsigned short* __restrict__ ws){
  int t = blockIdx.x * 256 + threadIdx.x;   // grid covers exactly 786432
  float v;
  if (t < 196608){
    int seg = t >> 16, r = t & 65535;
    int c = r & 255, d = (r >> 8) & 63, h = r >> 14;
    const float* W = (seg == 0) ? Wq : ((seg == 1) ? Wk : Wv);
    v = W[h*16384 + c*64 + d];
  } else if (t < 262144){
    int r = t - 196608; int n = r >> 8, c = r & 255;
    v = Wp[c*256 + n];
  } else if (t < 524288){
    int r = t - 262144; int n = r >> 8, c = r & 255;
    v = W1[c*1024 + n];
  } else {
    int r = t - 524288; int n = r >> 10, k = r & 1023;
    v = W2[k*256 + n];
  }
  ws[t] = f2bf(v);
}

// ---------------- attnproj_k: LN1 + attention + proj + residual --------------
// One 4-wave block per batch element; R1 phases A-C verbatim (proven 0.03125).
// LDS 64KB: h 32K | q/P 8K | k 8K | v^T 8K | per-wave P/att stripes 8K.
__global__ __launch_bounds__(256, 2) void attnproj_k(
    const float* __restrict__ x,
    const float* __restrict__ ln1g, const float* __restrict__ ln1b,
    const unsigned short* __restrict__ wqT,
    const unsigned short* __restrict__ wkT,
    const unsigned short* __restrict__ wvT,
    const unsigned short* __restrict__ wpT,
    const float* __restrict__ bpj,
    float* __restrict__ outp)
{
  __shared__ char smb[65536] __attribute__((aligned(16)));
  char* sm = smb;
  const int HLS = 0, QLS = 32768, KLS = 40960, VTLS = 49152, PATLS = 57344;

  const int b = blockIdx.x;
  const float* __restrict__ xb = x + (size_t)b * 16384;
  float* __restrict__ ob = outp + (size_t)b * 16384;
  const int tid = threadIdx.x;
  const int w = tid >> 6, l = tid & 63, m = l & 15, g = l >> 4;
  const v4f zf = {0.f, 0.f, 0.f, 0.f};

  // Phase A: LN1 -> h (bf16, LDS), 16 rows/wave
  {
    f4v lg = *(const f4v*)(ln1g + 4*l);
    f4v lb = *(const f4v*)(ln1b + 4*l);
    #pragma unroll
    for (int rr = 0; rr < 16; ++rr){
      int r = w*16 + rr;
      f4v xv = *(const f4v*)(xb + r*256 + 4*l);
      float s = xv[0]+xv[1]+xv[2]+xv[3];
      float q = xv[0]*xv[0]+xv[1]*xv[1]+xv[2]*xv[2]+xv[3]*xv[3];
      s = rsum64(s); q = rsum64(q);
      float mu = s * (1.f/256.f);
      float rs = rsqrtf(q * (1.f/256.f) - mu*mu + 1e-6f);
      u64 pk = 0;
      #pragma unroll
      for (int j = 0; j < 4; ++j){
        float hv = (xv[j] - mu) * rs * lg[j] + lb[j];
        pk |= (u64)f2bf(hv) << (16*j);
      }
      *(u64*)(sm + HLS + hoff(r, 4*l)) = pk;
    }
  }
  __syncthreads();

  // Phase B: attention; sa accumulated in regs
  v4f sa[4][4];
  #pragma unroll
  for (int i = 0; i < 4; ++i){
    #pragma unroll
    for (int j = 0; j < 4; ++j) sa[i][j] = zf;
  }

  #pragma unroll 1
  for (int hh = 0; hh < 4; ++hh){
    // QKV: wave w owns cols w*16..w*16+15 of q,k,v (shared A-fragments)
    {
      const unsigned short* bq = wqT + hh*16384 + (w*16 + m)*256;
      const unsigned short* bk = wkT + hh*16384 + (w*16 + m)*256;
      const unsigned short* bv = wvT + hh*16384 + (w*16 + m)*256;
      v4f qa[4] = {zf,zf,zf,zf}, ka[4] = {zf,zf,zf,zf}, va[4] = {zf,zf,zf,zf};
      #pragma unroll
      for (int ks = 0; ks < 8; ++ks){
        int k0 = ks*32 + 8*g;
        v4i bq4 = *(const v4i*)(bq + k0);
        v4i bk4 = *(const v4i*)(bk + k0);
        v4i bv4 = *(const v4i*)(bv + k0);
        #pragma unroll
        for (int rt = 0; rt < 4; ++rt){
          v4i af = *(const v4i*)(sm + HLS + hoff(rt*16 + m, k0));
          qa[rt] = mfma16(af, bq4, qa[rt]);
          ka[rt] = mfma16(af, bk4, ka[rt]);
          va[rt] = mfma16(af, bv4, va[rt]);
        }
      }
      #pragma unroll
      for (int rt = 0; rt < 4; ++rt){
        qa[rt] = accfence(qa[rt]); ka[rt] = accfence(ka[rt]); va[rt] = accfence(va[rt]);
        #pragma unroll
        for (int j = 0; j < 4; ++j){
          *(unsigned short*)(sm + QLS + koff(rt*16 + 4*g + j, w*16 + m)) = f2bf(qa[rt][j]);
          *(unsigned short*)(sm + KLS + koff(rt*16 + 4*g + j, w*16 + m)) = f2bf(ka[rt][j]);
        }
        *(u64*)(sm + VTLS + koff(w*16 + m, rt*16 + 4*g)) = pack4(va[rt]);  // V^T
      }
    }
    __syncthreads();   // bar1: q,k,v^T ready; prev-head PATLS readers done

    // S = Q K^T (stripe rows w*16..+15) -> softmax -> P -> PV -> own PATLS
    {
      v4f s4[4] = {zf,zf,zf,zf};
      #pragma unroll
      for (int ks = 0; ks < 2; ++ks){
        int k0 = ks*32 + 8*g;
        v4i qf = *(const v4i*)(sm + QLS + koff(w*16 + m, k0));
        #pragma unroll
        for (int nt = 0; nt < 4; ++nt){
          v4i kf = *(const v4i*)(sm + KLS + koff(nt*16 + m, k0));
          s4[nt] = mfma16(qf, kf, s4[nt]);
        }
      }
      #pragma unroll
      for (int nt = 0; nt < 4; ++nt) s4[nt] = accfence(s4[nt]);
      float mx[4] = {-3e38f, -3e38f, -3e38f, -3e38f};
      #pragma unroll
      for (int nt = 0; nt < 4; ++nt){
        #pragma unroll
        for (int j = 0; j < 4; ++j){
          int t = w*16 + 4*g + j, ss = nt*16 + m;
          float z = s4[nt][j] * 0.125f;
          z = (ss <= t) ? z : -1e30f;
          s4[nt][j] = z;
          mx[j] = fmaxf(mx[j], z);
        }
      }
      #pragma unroll
      for (int j = 0; j < 4; ++j) mx[j] = rmax16(mx[j]);
      float sum[4] = {0.f, 0.f, 0.f, 0.f};
      #pragma unroll
      for (int nt = 0; nt < 4; ++nt){
        #pragma unroll
        for (int j = 0; j < 4; ++j){
          float p = __expf(s4[nt][j] - mx[j]);
          s4[nt][j] = p;
          sum[j] += p;
        }
      }
      #pragma unroll
      for (int j = 0; j < 4; ++j) sum[j] = 1.f / rsum16(sum[j]);
      #pragma unroll
      for (int nt = 0; nt < 4; ++nt){
        #pragma unroll
        for (int j = 0; j < 4; ++j)
          *(unsigned short*)(sm + PATLS + w*2048 + koff(4*g + j, nt*16 + m)) =
              f2bf(s4[nt][j] * sum[j]);
      }
      v4f av[4] = {zf,zf,zf,zf};
      #pragma unroll
      for (int ks = 0; ks < 2; ++ks){
        int k0 = ks*32 + 8*g;
        v4i pf = *(const v4i*)(sm + PATLS + w*2048 + koff(m, k0));
        #pragma unroll
        for (int nt = 0; nt < 4; ++nt){
          v4i vf = *(const v4i*)(sm + VTLS + koff(nt*16 + m, k0));
          av[nt] = mfma16(pf, vf, av[nt]);
        }
      }
      #pragma unroll
      for (int nt = 0; nt < 4; ++nt) av[nt] = accfence(av[nt]);
      #pragma unroll
      for (int nt = 0; nt < 4; ++nt){
        #pragma unroll
        for (int j = 0; j < 4; ++j)
          *(unsigned short*)(sm + PATLS + w*2048 + koff(4*g + j, nt*16 + m)) =
              f2bf(av[nt][j]);
      }
    }
    __syncthreads();   // bar2: att stripes ready

    // proj: sa += att_head @ Wproj[64*hh:, :]; wave w owns cols w*64..w*64+63
    #pragma unroll
    for (int ks = 0; ks < 2; ++ks){
      int k0 = ks*32 + 8*g;
      v4i af2[4];
      #pragma unroll
      for (int rt = 0; rt < 4; ++rt)
        af2[rt] = *(const v4i*)(sm + PATLS + rt*2048 + koff(m, k0));
      #pragma unroll
      for (int nt = 0; nt < 4; ++nt){
        v4i bp = *(const v4i*)(wpT + (w*64 + nt*16 + m)*256 + hh*64 + k0);
        #pragma unroll
        for (int rt = 0; rt < 4; ++rt) sa[rt][nt] = mfma16(af2[rt], bp, sa[rt][nt]);
      }
    }
    // no trailing barrier: next head's QLS/KLS/VTLS writes are disjoint from
    // PATLS; PATLS next written after next bar1 (all waves past this point).
  }

  // Phase C residual: x2 = x + sa + bproj -> f32 in d_out
  {
    #pragma unroll
    for (int i = 0; i < 4; ++i){
      #pragma unroll
      for (int j = 0; j < 4; ++j) sa[i][j] = accfence(sa[i][j]);
    }
    float bp4[4];
    #pragma unroll
    for (int nt = 0; nt < 4; ++nt) bp4[nt] = bpj[w*64 + nt*16 + m];
    #pragma unroll
    for (int rt = 0; rt < 4; ++rt){
      #pragma unroll
      for (int j = 0; j < 4; ++j){
        int row = rt*16 + 4*g + j;
        #pragma unroll
        for (int nt = 0; nt < 4; ++nt){
          int col = w*64 + nt*16 + m;
          ob[row*256 + col] = xb[row*256 + col] + sa[rt][nt][j] + bp4[nt];
        }
      }
    }
  }
}

// ---------------- mlp_k: LN2(x2) -> MLP -> out = x2 + ff + b2 (RMW) ----------
// Ping-pong act buffers: 1 barrier per chunk (9 total vs R1's 17).
__global__ __launch_bounds__(256, 2) void mlp_k(
    const float* __restrict__ ln2g, const float* __restrict__ ln2b,
    const unsigned short* __restrict__ w1T,
    const float* __restrict__ b1,
    const unsigned short* __restrict__ w2T,
    const float* __restrict__ b2,
    float* __restrict__ outp)
{
  __shared__ char smb[65536] __attribute__((aligned(16)));
  char* sm = smb;
  const int HLS = 0;                       // h2 [64][256] bf16 swz
  const int ACT0 = 32768, ACT1 = 49152;    // act chunks [64][128] bf16 swz
  const int b = blockIdx.x;
  float* __restrict__ ob = outp + (size_t)b * 16384;
  const int tid = threadIdx.x;
  const int w = tid >> 6, l = tid & 63, m = l & 15, g = l >> 4;
  const v4f zf = {0.f, 0.f, 0.f, 0.f};

  // LN2 from x2 (f32 in d_out) -> h2 (bf16, LDS); same pattern as LN1
  {
    f4v lg = *(const f4v*)(ln2g + 4*l);
    f4v lb = *(const f4v*)(ln2b + 4*l);
    #pragma unroll
    for (int rr = 0; rr < 16; ++rr){
      int r = w*16 + rr;
      f4v xv = *(const f4v*)(ob + r*256 + 4*l);
      float s = xv[0]+xv[1]+xv[2]+xv[3];
      float q = xv[0]*xv[0]+xv[1]*xv[1]+xv[2]*xv[2]+xv[3]*xv[3];
      s = rsum64(s); q = rsum64(q);
      float mu = s * (1.f/256.f);
      float rs = rsqrtf(q * (1.f/256.f) - mu*mu + 1e-6f);
      u64 pk = 0;
      #pragma unroll
      for (int j = 0; j < 4; ++j){
        float hv = (xv[j] - mu) * rs * lg[j] + lb[j];
        pk |= (u64)f2bf(hv) << (16*j);
      }
      *(u64*)(sm + HLS + hoff(r, 4*l)) = pk;
    }
  }
  __syncthreads();

  v4f ff[4][4];
  #pragma unroll
  for (int i = 0; i < 4; ++i){
    #pragma unroll
    for (int j = 0; j < 4; ++j) ff[i][j] = zf;
  }

  #pragma unroll 1
  for (int ch = 0; ch < 8; ++ch){
    const int ACT = (ch & 1) ? ACT1 : ACT0;
    // GEMM1: act chunk cols ch*128..+127; wave w -> 32 cols
    v4f a1[4][2];
    #pragma unroll
    for (int i = 0; i < 4; ++i){ a1[i][0] = zf; a1[i][1] = zf; }
    const unsigned short* w1a = w1T + (ch*128 + w*32 +      m)*256;
    const unsigned short* w1b = w1T + (ch*128 + w*32 + 16 + m)*256;
    #pragma unroll
    for (int ks = 0; ks < 8; ++ks){
      int k0 = ks*32 + 8*g;
      v4i bw0 = *(const v4i*)(w1a + k0);
      v4i bw1 = *(const v4i*)(w1b + k0);
      #pragma unroll
      for (int rt = 0; rt < 4; ++rt){
        v4i af = *(const v4i*)(sm + HLS + hoff(rt*16 + m, k0));
        a1[rt][0] = mfma16(af, bw0, a1[rt][0]);
        a1[rt][1] = mfma16(af, bw1, a1[rt][1]);
      }
    }
    float b1v[2] = { b1[ch*128 + w*32 + m], b1[ch*128 + w*32 + 16 + m] };
    #pragma unroll
    for (int i = 0; i < 4; ++i){ a1[i][0] = accfence(a1[i][0]); a1[i][1] = accfence(a1[i][1]); }
    #pragma unroll
    for (int rt = 0; rt < 4; ++rt){
      #pragma unroll
      for (int j = 0; j < 4; ++j){
        int row = rt*16 + 4*g + j;
        #pragma unroll
        for (int nt = 0; nt < 2; ++nt){
          float v = fmaxf(a1[rt][nt][j] + b1v[nt], 0.f);
          *(unsigned short*)(sm + ACT + aoff(row, w*32 + nt*16 + m)) = f2bf(v);
        }
      }
    }
    __syncthreads();   // the ONLY barrier per chunk (ping-pong makes it safe)
    // GEMM2: ff += act_chunk @ W2T[:, ch*128..]; wave w -> 64 cols
    #pragma unroll
    for (int ks = 0; ks < 4; ++ks){
      int k0 = ks*32 + 8*g;
      v4i af[4];
      #pragma unroll
      for (int rt = 0; rt < 4; ++rt)
        af[rt] = *(const v4i*)(sm + ACT + aoff(rt*16 + m, k0));
      #pragma unroll
      for (int nt = 0; nt < 4; ++nt){
        v4i bw = *(const v4i*)(w2T + (w*64 + nt*16 + m)*1024 + ch*128 + k0);
        #pragma unroll
        for (int rt = 0; rt < 4; ++rt) ff[rt][nt] = mfma16(af[rt], bw, ff[rt][nt]);
      }
    }
  }

  {
    float b2v[4];
    #pragma unroll
    for (int nt = 0; nt < 4; ++nt) b2v[nt] = b2[w*64 + nt*16 + m];
    #pragma unroll
    for (int i = 0; i < 4; ++i){
      #pragma unroll
      for (int j = 0; j < 4; ++j) ff[i][j] = accfence(ff[i][j]);
    }
    #pragma unroll
    for (int rt = 0; rt < 4; ++rt){
      #pragma unroll
      for (int j = 0; j < 4; ++j){
        int row = rt*16 + 4*g + j;
        #pragma unroll
        for (int nt = 0; nt < 4; ++nt){
          int col = w*64 + nt*16 + m;
          ob[row*256 + col] += ff[rt][nt][j] + b2v[nt];
        }
      }
    }
  }
}

extern "C" void kernel_launch(void* const* d_in, const int* in_sizes, int n_in,
                              void* d_out, int out_size, void* d_ws, size_t ws_size,
                              hipStream_t stream) {
  const float* x    = (const float*)d_in[0];
  const float* ln1g = (const float*)d_in[1];
  const float* ln1b = (const float*)d_in[2];
  const float* Wq   = (const float*)d_in[3];
  const float* Wk   = (const float*)d_in[4];
  const float* Wv   = (const float*)d_in[5];
  const float* Wp   = (const float*)d_in[6];
  const float* bpj  = (const float*)d_in[7];
  const float* ln2g = (const float*)d_in[8];
  const float* ln2b = (const float*)d_in[9];
  const float* W1   = (const float*)d_in[10];
  const float* b1   = (const float*)d_in[11];
  const float* W2   = (const float*)d_in[12];
  const float* b2   = (const float*)d_in[13];
  unsigned short* ws = (unsigned short*)d_ws;
  float* outp = (float*)d_out;

  prep_w<<<3072, 256, 0, stream>>>(Wq, Wk, Wv, Wp, W1, W2, ws);
  attnproj_k<<<4096, 256, 0, stream>>>(x, ln1g, ln1b,
                                       ws, ws + 65536, ws + 131072, ws + 196608,
                                       bpj, outp);
  mlp_k<<<4096, 256, 0, stream>>>(ln2g, ln2b, ws + 262144, b1,
                                  ws + 524288, b2, outp);
}

// Round 9
// 897.823 us; speedup vs baseline: 1.4507x; 1.0757x over previous
//
#include <hip/hip_runtime.h>
#include <hip/hip_bf16.h>

// Fused transformer block as a 3-kernel pipeline:
//   prep_w     : f32 weights -> bf16 transposed in ws (1.5 MB only).
//   attnproj_k : LN1 -> per-head (QKV -> causal softmax -> PV -> proj-accum
//                in regs) -> x2 = x + sa + bproj -> f32 in d_out. R1-proven.
//   mlp_k      : 2 batch elems/block (M=128): LN2(x2) -> MLP -> RMW out.
// All intra-kernel barriers are lgkm-only (s_waitcnt lgkmcnt(0); s_barrier):
// every barrier here orders LDS-only data, so read-only global weight loads
// legally stay in flight across barriers (avoids the vmcnt(0) drain that
// __syncthreads forces -- the ~20% stall documented in the guide).
// ws layout (bf16/ushort): [0,65536) WqT[h][d][c]; [65536,131072) WkT;
// [131072,196608) WvT; [196608,262144) WprojT[n][c]; [262144,524288) W1T[n][c];
// [524288,786432) W2T[n][k].  Requires ws_size >= 1572864 bytes only.

typedef float v4f __attribute__((ext_vector_type(4)));
typedef int   v4i __attribute__((ext_vector_type(4)));
typedef float f4v __attribute__((ext_vector_type(4)));
typedef unsigned long long u64;

#define DEV static __device__ __forceinline__

DEV unsigned short f2bf(float f){
  return __builtin_bit_cast(unsigned short, __float2bfloat16(f));
}

// lgkm-only workgroup barrier: orders LDS traffic, leaves global loads in
// flight. Safe because all cross-wave data in these kernels flows via LDS.
DEV void bar(){
  asm volatile("s_waitcnt lgkmcnt(0)\n\ts_barrier" ::: "memory");
}

// bf16 MFMA via inline asm: layout-safe under consistent per-lane contiguous-8
// K fragments (A from [M][K] rows, B from [N][K] rows i.e. pre-transposed).
DEV v4f mfma16(v4i a, v4i b, v4f c){
  asm("v_mfma_f32_16x16x32_bf16 %0, %1, %2, %0" : "+v"(c) : "v"(a), "v"(b));
  return c;
}
// Hazard fence: asm MFMA is opaque to the hazard recognizer.
DEV v4f accfence(v4f c){
  asm("s_nop 7\n\ts_nop 3" : "+v"(c));
  return c;
}

// Swizzled LDS byte offsets (XOR row bits into 16B-granule bits).
DEV int hoff(int r, int c){ return r*512 + ((c*2) ^ ((r & 7) << 4)); }  // [*][256] bf16
DEV int koff(int r, int c){ return r*128 + ((c*2) ^ ((r & 7) << 4)); }  // [*][64]  bf16

DEV u64 pack4(v4f v){
  return (u64)f2bf(v[0]) | ((u64)f2bf(v[1]) << 16)
       | ((u64)f2bf(v[2]) << 32) | ((u64)f2bf(v[3]) << 48);
}

DEV float rsum64(float v){
  #pragma unroll
  for (int k = 1; k < 64; k <<= 1) v += __shfl_xor(v, k);
  return v;
}
DEV float rsum16(float v){
  #pragma unroll
  for (int k = 1; k < 16; k <<= 1) v += __shfl_xor(v, k);
  return v;
}
DEV float rmax16(float v){
  #pragma unroll
  for (int k = 1; k < 16; k <<= 1) v = fmaxf(v, __shfl_xor(v, k));
  return v;
}

__global__ void prep_w(const float* __restrict__ Wq, const float* __restrict__ Wk,
                       const float* __restrict__ Wv, const float* __restrict__ Wp,
                       const float* __restrict__ W1, const float* __restrict__ W2,
                       unsigned short* __restrict__ ws){
  int t = blockIdx.x * 256 + threadIdx.x;   // grid covers exactly 786432
  float v;
  if (t < 196608){
    int seg = t >> 16, r = t & 65535;
    int c = r & 255, d = (r >> 8) & 63, h = r >> 14;
    const float* W = (seg == 0) ? Wq : ((seg == 1) ? Wk : Wv);
    v = W[h*16384 + c*64 + d];
  } else if (t < 262144){
    int r = t - 196608; int n = r >> 8, c = r & 255;
    v = Wp[c*256 + n];
  } else if (t < 524288){
    int r = t - 262144; int n = r >> 8, c = r & 255;
    v = W1[c*1024 + n];
  } else {
    int r = t - 524288; int n = r >> 10, k = r & 1023;
    v = W2[k*256 + n];
  }
  ws[t] = f2bf(v);
}

// ---------------- attnproj_k: LN1 + attention + proj + residual --------------
// One 4-wave block per batch element; R1 phases A-C verbatim (proven numerics).
// LDS 64KB: h 32K | q/P 8K | k 8K | v^T 8K | per-wave P/att stripes 8K.
__global__ __launch_bounds__(256, 2) void attnproj_k(
    const float* __restrict__ x,
    const float* __restrict__ ln1g, const float* __restrict__ ln1b,
    const unsigned short* __restrict__ wqT,
    const unsigned short* __restrict__ wkT,
    const unsigned short* __restrict__ wvT,
    const unsigned short* __restrict__ wpT,
    const float* __restrict__ bpj,
    float* __restrict__ outp)
{
  __shared__ char smb[65536] __attribute__((aligned(16)));
  char* sm = smb;
  const int HLS = 0, QLS = 32768, KLS = 40960, VTLS = 49152, PATLS = 57344;

  const int b = blockIdx.x;
  const float* __restrict__ xb = x + (size_t)b * 16384;
  float* __restrict__ ob = outp + (size_t)b * 16384;
  const int tid = threadIdx.x;
  const int w = tid >> 6, l = tid & 63, m = l & 15, g = l >> 4;
  const v4f zf = {0.f, 0.f, 0.f, 0.f};

  // Phase A: LN1 -> h (bf16, LDS), 16 rows/wave
  {
    f4v lg = *(const f4v*)(ln1g + 4*l);
    f4v lb = *(const f4v*)(ln1b + 4*l);
    #pragma unroll
    for (int rr = 0; rr < 16; ++rr){
      int r = w*16 + rr;
      f4v xv = *(const f4v*)(xb + r*256 + 4*l);
      float s = xv[0]+xv[1]+xv[2]+xv[3];
      float q = xv[0]*xv[0]+xv[1]*xv[1]+xv[2]*xv[2]+xv[3]*xv[3];
      s = rsum64(s); q = rsum64(q);
      float mu = s * (1.f/256.f);
      float rs = rsqrtf(q * (1.f/256.f) - mu*mu + 1e-6f);
      u64 pk = 0;
      #pragma unroll
      for (int j = 0; j < 4; ++j){
        float hv = (xv[j] - mu) * rs * lg[j] + lb[j];
        pk |= (u64)f2bf(hv) << (16*j);
      }
      *(u64*)(sm + HLS + hoff(r, 4*l)) = pk;
    }
  }
  bar();

  // Phase B: attention; sa accumulated in regs
  v4f sa[4][4];
  #pragma unroll
  for (int i = 0; i < 4; ++i){
    #pragma unroll
    for (int j = 0; j < 4; ++j) sa[i][j] = zf;
  }

  #pragma unroll 1
  for (int hh = 0; hh < 4; ++hh){
    // QKV: wave w owns cols w*16..w*16+15 of q,k,v (shared A-fragments)
    {
      const unsigned short* bq = wqT + hh*16384 + (w*16 + m)*256;
      const unsigned short* bk = wkT + hh*16384 + (w*16 + m)*256;
      const unsigned short* bv = wvT + hh*16384 + (w*16 + m)*256;
      v4f qa[4] = {zf,zf,zf,zf}, ka[4] = {zf,zf,zf,zf}, va[4] = {zf,zf,zf,zf};
      #pragma unroll
      for (int ks = 0; ks < 8; ++ks){
        int k0 = ks*32 + 8*g;
        v4i bq4 = *(const v4i*)(bq + k0);
        v4i bk4 = *(const v4i*)(bk + k0);
        v4i bv4 = *(const v4i*)(bv + k0);
        #pragma unroll
        for (int rt = 0; rt < 4; ++rt){
          v4i af = *(const v4i*)(sm + HLS + hoff(rt*16 + m, k0));
          qa[rt] = mfma16(af, bq4, qa[rt]);
          ka[rt] = mfma16(af, bk4, ka[rt]);
          va[rt] = mfma16(af, bv4, va[rt]);
        }
      }
      #pragma unroll
      for (int rt = 0; rt < 4; ++rt){
        qa[rt] = accfence(qa[rt]); ka[rt] = accfence(ka[rt]); va[rt] = accfence(va[rt]);
        #pragma unroll
        for (int j = 0; j < 4; ++j){
          *(unsigned short*)(sm + QLS + koff(rt*16 + 4*g + j, w*16 + m)) = f2bf(qa[rt][j]);
          *(unsigned short*)(sm + KLS + koff(rt*16 + 4*g + j, w*16 + m)) = f2bf(ka[rt][j]);
        }
        *(u64*)(sm + VTLS + koff(w*16 + m, rt*16 + 4*g)) = pack4(va[rt]);  // V^T
      }
    }
    bar();   // bar1: q,k,v^T ready; prev-head PATLS readers done

    // S = Q K^T (stripe rows w*16..+15) -> softmax -> P -> PV -> own PATLS
    {
      v4f s4[4] = {zf,zf,zf,zf};
      #pragma unroll
      for (int ks = 0; ks < 2; ++ks){
        int k0 = ks*32 + 8*g;
        v4i qf = *(const v4i*)(sm + QLS + koff(w*16 + m, k0));
        #pragma unroll
        for (int nt = 0; nt < 4; ++nt){
          v4i kf = *(const v4i*)(sm + KLS + koff(nt*16 + m, k0));
          s4[nt] = mfma16(qf, kf, s4[nt]);
        }
      }
      #pragma unroll
      for (int nt = 0; nt < 4; ++nt) s4[nt] = accfence(s4[nt]);
      float mx[4] = {-3e38f, -3e38f, -3e38f, -3e38f};
      #pragma unroll
      for (int nt = 0; nt < 4; ++nt){
        #pragma unroll
        for (int j = 0; j < 4; ++j){
          int t = w*16 + 4*g + j, ss = nt*16 + m;
          float z = s4[nt][j] * 0.125f;
          z = (ss <= t) ? z : -1e30f;
          s4[nt][j] = z;
          mx[j] = fmaxf(mx[j], z);
        }
      }
      #pragma unroll
      for (int j = 0; j < 4; ++j) mx[j] = rmax16(mx[j]);
      float sum[4] = {0.f, 0.f, 0.f, 0.f};
      #pragma unroll
      for (int nt = 0; nt < 4; ++nt){
        #pragma unroll
        for (int j = 0; j < 4; ++j){
          float p = __expf(s4[nt][j] - mx[j]);
          s4[nt][j] = p;
          sum[j] += p;
        }
      }
      #pragma unroll
      for (int j = 0; j < 4; ++j) sum[j] = 1.f / rsum16(sum[j]);
      #pragma unroll
      for (int nt = 0; nt < 4; ++nt){
        #pragma unroll
        for (int j = 0; j < 4; ++j)
          *(unsigned short*)(sm + PATLS + w*2048 + koff(4*g + j, nt*16 + m)) =
              f2bf(s4[nt][j] * sum[j]);
      }
      v4f av[4] = {zf,zf,zf,zf};
      #pragma unroll
      for (int ks = 0; ks < 2; ++ks){
        int k0 = ks*32 + 8*g;
        v4i pf = *(const v4i*)(sm + PATLS + w*2048 + koff(m, k0));
        #pragma unroll
        for (int nt = 0; nt < 4; ++nt){
          v4i vf = *(const v4i*)(sm + VTLS + koff(nt*16 + m, k0));
          av[nt] = mfma16(pf, vf, av[nt]);
        }
      }
      #pragma unroll
      for (int nt = 0; nt < 4; ++nt) av[nt] = accfence(av[nt]);
      #pragma unroll
      for (int nt = 0; nt < 4; ++nt){
        #pragma unroll
        for (int j = 0; j < 4; ++j)
          *(unsigned short*)(sm + PATLS + w*2048 + koff(4*g + j, nt*16 + m)) =
              f2bf(av[nt][j]);
      }
    }
    bar();   // bar2: att stripes ready

    // proj: sa += att_head @ Wproj[64*hh:, :]; wave w owns cols w*64..w*64+63
    #pragma unroll
    for (int ks = 0; ks < 2; ++ks){
      int k0 = ks*32 + 8*g;
      v4i af2[4];
      #pragma unroll
      for (int rt = 0; rt < 4; ++rt)
        af2[rt] = *(const v4i*)(sm + PATLS + rt*2048 + koff(m, k0));
      #pragma unroll
      for (int nt = 0; nt < 4; ++nt){
        v4i bp = *(const v4i*)(wpT + (w*64 + nt*16 + m)*256 + hh*64 + k0);
        #pragma unroll
        for (int rt = 0; rt < 4; ++rt) sa[rt][nt] = mfma16(af2[rt], bp, sa[rt][nt]);
      }
    }
    // no trailing barrier: next head's QLS/KLS/VTLS writes are disjoint from
    // PATLS; PATLS next written after next bar1 (all waves past this point).
  }

  // Phase C residual: x2 = x + sa + bproj -> f32 in d_out
  {
    #pragma unroll
    for (int i = 0; i < 4; ++i){
      #pragma unroll
      for (int j = 0; j < 4; ++j) sa[i][j] = accfence(sa[i][j]);
    }
    float bp4[4];
    #pragma unroll
    for (int nt = 0; nt < 4; ++nt) bp4[nt] = bpj[w*64 + nt*16 + m];
    #pragma unroll
    for (int rt = 0; rt < 4; ++rt){
      #pragma unroll
      for (int j = 0; j < 4; ++j){
        int row = rt*16 + 4*g + j;
        #pragma unroll
        for (int nt = 0; nt < 4; ++nt){
          int col = w*64 + nt*16 + m;
          ob[row*256 + col] = xb[row*256 + col] + sa[rt][nt][j] + bp4[nt];
        }
      }
    }
  }
}

// ---------------- mlp_k: 2 batch elems/block (M=128) -------------------------
// LDS 128KB dynamic: h2 [128][256] bf16 @0 (64K) | act [128][256] bf16 @64K.
// 8 waves; wave w owns 32 N-cols per GEMM. 4 chunks x (GEMM1, bar, GEMM2, bar).
// Each weight fragment feeds 8 MFMA (rt=0..7) -- 2x R8's amortization; weight
// L2 traffic halves (2048 blocks x 1MB).
#define MLP_LDS 131072
__global__ __launch_bounds__(512, 1) void mlp_k(
    const float* __restrict__ ln2g, const float* __restrict__ ln2b,
    const unsigned short* __restrict__ w1T,
    const float* __restrict__ b1,
    const unsigned short* __restrict__ w2T,
    const float* __restrict__ b2,
    float* __restrict__ outp)
{
  extern __shared__ char sm[];
  const int HLS = 0, ACT = 65536;
  const int bb = blockIdx.x;               // 2-batch slab
  float* __restrict__ ob = outp + (size_t)bb * 32768;
  const int tid = threadIdx.x;
  const int w = tid >> 6, l = tid & 63, m = l & 15, g = l >> 4;
  const v4f zf = {0.f, 0.f, 0.f, 0.f};

  // LN2 from x2 (f32 in d_out) -> h2 (bf16, LDS); 8 waves x 16 rows = 128
  {
    f4v lg = *(const f4v*)(ln2g + 4*l);
    f4v lb = *(const f4v*)(ln2b + 4*l);
    #pragma unroll
    for (int rr = 0; rr < 16; ++rr){
      int r = w*16 + rr;
      f4v xv = *(const f4v*)(ob + r*256 + 4*l);
      float s = xv[0]+xv[1]+xv[2]+xv[3];
      float q = xv[0]*xv[0]+xv[1]*xv[1]+xv[2]*xv[2]+xv[3]*xv[3];
      s = rsum64(s); q = rsum64(q);
      float mu = s * (1.f/256.f);
      float rs = rsqrtf(q * (1.f/256.f) - mu*mu + 1e-6f);
      u64 pk = 0;
      #pragma unroll
      for (int j = 0; j < 4; ++j){
        float hv = (xv[j] - mu) * rs * lg[j] + lb[j];
        pk |= (u64)f2bf(hv) << (16*j);
      }
      *(u64*)(sm + HLS + hoff(r, 4*l)) = pk;
    }
  }
  bar();

  v4f ff[8][2];
  #pragma unroll
  for (int i = 0; i < 8; ++i){ ff[i][0] = zf; ff[i][1] = zf; }

  #pragma unroll 1
  for (int ch = 0; ch < 4; ++ch){
    // GEMM1: act[:, ch*256..+255]; wave w -> cols w*32..w*32+31 of the chunk
    v4f a1[8][2];
    #pragma unroll
    for (int i = 0; i < 8; ++i){ a1[i][0] = zf; a1[i][1] = zf; }
    const unsigned short* w1a = w1T + (ch*256 + w*32 +      m)*256;
    const unsigned short* w1b = w1T + (ch*256 + w*32 + 16 + m)*256;
    #pragma unroll
    for (int ks = 0; ks < 8; ++ks){
      int k0 = ks*32 + 8*g;
      v4i bw0 = *(const v4i*)(w1a + k0);
      v4i bw1 = *(const v4i*)(w1b + k0);
      #pragma unroll
      for (int rt = 0; rt < 8; ++rt){
        v4i af = *(const v4i*)(sm + HLS + hoff(rt*16 + m, k0));
        a1[rt][0] = mfma16(af, bw0, a1[rt][0]);
        a1[rt][1] = mfma16(af, bw1, a1[rt][1]);
      }
    }
    float b1v[2] = { b1[ch*256 + w*32 + m], b1[ch*256 + w*32 + 16 + m] };
    #pragma unroll
    for (int i = 0; i < 8; ++i){ a1[i][0] = accfence(a1[i][0]); a1[i][1] = accfence(a1[i][1]); }
    #pragma unroll
    for (int rt = 0; rt < 8; ++rt){
      #pragma unroll
      for (int j = 0; j < 4; ++j){
        int row = rt*16 + 4*g + j;
        #pragma unroll
        for (int nt = 0; nt < 2; ++nt){
          float v = fmaxf(a1[rt][nt][j] + b1v[nt], 0.f);
          *(unsigned short*)(sm + ACT + hoff(row, w*32 + nt*16 + m)) = f2bf(v);
        }
      }
    }
    bar();   // act chunk ready

    // GEMM2: ff += act_chunk @ W2T[:, ch*256..]; wave w -> cols w*32..w*32+31
    #pragma unroll
    for (int ks = 0; ks < 8; ++ks){
      int k0 = ks*32 + 8*g;
      v4i af[8];
      #pragma unroll
      for (int rt = 0; rt < 8; ++rt)
        af[rt] = *(const v4i*)(sm + ACT + hoff(rt*16 + m, k0));
      #pragma unroll
      for (int nt = 0; nt < 2; ++nt){
        v4i bw = *(const v4i*)(w2T + (w*32 + nt*16 + m)*1024 + ch*256 + k0);
        #pragma unroll
        for (int rt = 0; rt < 8; ++rt) ff[rt][nt] = mfma16(af[rt], bw, ff[rt][nt]);
      }
    }
    bar();   // protect act before next chunk's GEMM1 overwrite
  }

  {
    float b2v[2] = { b2[w*32 + m], b2[w*32 + 16 + m] };
    #pragma unroll
    for (int i = 0; i < 8; ++i){ ff[i][0] = accfence(ff[i][0]); ff[i][1] = accfence(ff[i][1]); }
    #pragma unroll
    for (int rt = 0; rt < 8; ++rt){
      #pragma unroll
      for (int j = 0; j < 4; ++j){
        int row = rt*16 + 4*g + j;
        #pragma unroll
        for (int nt = 0; nt < 2; ++nt){
          int col = w*32 + nt*16 + m;
          ob[row*256 + col] += ff[rt][nt][j] + b2v[nt];
        }
      }
    }
  }
}

extern "C" void kernel_launch(void* const* d_in, const int* in_sizes, int n_in,
                              void* d_out, int out_size, void* d_ws, size_t ws_size,
                              hipStream_t stream) {
  const float* x    = (const float*)d_in[0];
  const float* ln1g = (const float*)d_in[1];
  const float* ln1b = (const float*)d_in[2];
  const float* Wq   = (const float*)d_in[3];
  const float* Wk   = (const float*)d_in[4];
  const float* Wv   = (const float*)d_in[5];
  const float* Wp   = (const float*)d_in[6];
  const float* bpj  = (const float*)d_in[7];
  const float* ln2g = (const float*)d_in[8];
  const float* ln2b = (const float*)d_in[9];
  const float* W1   = (const float*)d_in[10];
  const float* b1   = (const float*)d_in[11];
  const float* W2   = (const float*)d_in[12];
  const float* b2   = (const float*)d_in[13];
  unsigned short* ws = (unsigned short*)d_ws;
  float* outp = (float*)d_out;

  hipFuncSetAttribute((const void*)mlp_k,
                      hipFuncAttributeMaxDynamicSharedMemorySize, MLP_LDS);

  prep_w<<<3072, 256, 0, stream>>>(Wq, Wk, Wv, Wp, W1, W2, ws);
  attnproj_k<<<4096, 256, 0, stream>>>(x, ln1g, ln1b,
                                       ws, ws + 65536, ws + 131072, ws + 196608,
                                       bpj, outp);
  mlp_k<<<2048, 512, MLP_LDS, stream>>>(ln2g, ln2b, ws + 262144, b1,
                                        ws + 524288, b2, outp);
}